// Round 6
// baseline (932.361 us; speedup 1.0000x reference)
//
#include <hip/hip_runtime.h>
#include <hip/hip_bf16.h>

typedef __attribute__((ext_vector_type(8))) __bf16 bf16x8;
typedef __attribute__((ext_vector_type(4))) __bf16 bf16x4;
typedef __attribute__((ext_vector_type(16))) float f32x16;

#define D_IN   2048
#define D_FF   8192
#define D_OUT  2048
#define BATCH  4096
#define SIZE_N 5794
#define SIZE_M 2897
// padded GEMM1 dims
#define PN 5888   // 23*256 = 46*128
#define PK 2944   // 46*64  (BK=64 tiles)

#define OFF_B1 16777216
#define OFF_W2 16785408
#define OFF_B2 33562624

#define BK 64

__device__ __forceinline__ void gload_lds16(const __bf16* g, __bf16* lds) {
    __builtin_amdgcn_global_load_lds(
        (const __attribute__((address_space(1))) void*)g,
        (__attribute__((address_space(3))) void*)lds,
        16, 0, 0);
}

// ---------------------------------------------------------------------------
// BIG kernel: block tile 256x128, 4 waves in 2x2, wave tile 128x64 (4x2
// blocking of 32x32x16 MFMA). 0.75 ds_read per MFMA (vs 1.0 in the 128x128
// kernel) — LDS read pipe (measured ~12 cyc/read incl. the constant 4-cyc
// penalty R1/R3/R5 all show) drops below matrix-pipe parity.
// LDS rows = 128 B; chunk c of row r at slot c ^ (r&7).
// MODE 0: store bf16, bounds-checked, no bias; MODE 1: +bias, relu, bf16.
// ---------------------------------------------------------------------------
template<int MODE>
__global__ __launch_bounds__(256)
void gemm_nt_big(const __bf16* __restrict__ A, int lda,
                 const __bf16* __restrict__ B, int ldb,
                 void* __restrict__ Cv, int ldc,
                 const __bf16* __restrict__ bias,
                 int K, int Mvalid, int Nvalid)
{
    __shared__ bf16x8 As[256 * 8];   // 32 KB
    __shared__ bf16x8 Bs[128 * 8];   // 16 KB

    const int tid  = threadIdx.x;
    const int wave = tid >> 6;
    const int lane = tid & 63;

    const int bm0 = blockIdx.x * 256;
    const int bn0 = blockIdx.y * 128;

    const int wr = wave >> 1;   // row half: 128 rows
    const int wc = wave & 1;    // col half: 64 cols

    // staging: wave stages A rows [64*wave, 64*wave+64) (8 gloads) and
    // B rows [32*wave, 32*wave+32) (4 gloads). Lane L fetches chunk
    // (L&7)^(L>>3) of row base+(L>>3) so LDS slot sl of row r holds c=sl^(r&7).
    const int srow8 = lane >> 3;                    // 0..7
    const int sc8   = ((lane & 7) ^ srow8) * 8;     // swizzled chunk (elems)

    const __bf16* aptr = A + (size_t)(bm0 + wave * 64 + srow8) * lda + sc8;
    const __bf16* bptr = B + (size_t)(bn0 + wave * 32 + srow8) * ldb + sc8;

    // fragment read indices
    const int fr  = lane & 31;
    const int kh  = lane >> 5;
    const int frs = fr & 7;
    int aRow[4], bRow[2];
    #pragma unroll
    for (int i = 0; i < 4; ++i) aRow[i] = (wr * 128 + i * 32 + fr) * 8;
    #pragma unroll
    for (int j = 0; j < 2; ++j) bRow[j] = (wc * 64 + j * 32 + fr) * 8;

    f32x16 acc[4][2] = {};

    const int kTiles = K / BK;
    for (int kt = 0; kt < kTiles; ++kt) {
        #pragma unroll
        for (int i = 0; i < 8; ++i)
            gload_lds16(aptr + (size_t)(8 * i) * lda,
                        (__bf16*)&As[(wave * 64 + 8 * i) * 8]);
        #pragma unroll
        for (int i = 0; i < 4; ++i)
            gload_lds16(bptr + (size_t)(8 * i) * ldb,
                        (__bf16*)&Bs[(wave * 32 + 8 * i) * 8]);
        aptr += BK;
        bptr += BK;
        __builtin_amdgcn_s_waitcnt(0);
        __syncthreads();

        #pragma unroll
        for (int w = 0; w < 4; ++w) {
            const int sl = (2 * w + kh) ^ frs;
            bf16x8 b0 = Bs[bRow[0] + sl];
            bf16x8 b1 = Bs[bRow[1] + sl];
            #pragma unroll
            for (int i = 0; i < 4; ++i) {
                bf16x8 a = As[aRow[i] + sl];
                acc[i][0] = __builtin_amdgcn_mfma_f32_32x32x16_bf16(a, b0, acc[i][0], 0, 0, 0);
                acc[i][1] = __builtin_amdgcn_mfma_f32_32x32x16_bf16(a, b1, acc[i][1], 0, 0, 0);
            }
        }

        __syncthreads();
    }

    // epilogue: C/D layout col=lane&31, row=(reg&3)+8*(reg>>2)+4*(lane>>5)
    const int ecol  = lane & 31;
    const int erow0 = 4 * kh;
    #pragma unroll
    for (int i = 0; i < 4; ++i) {
        #pragma unroll
        for (int j = 0; j < 2; ++j) {
            const int colBase = bn0 + wc * 64 + j * 32 + ecol;
            #pragma unroll
            for (int reg = 0; reg < 16; ++reg) {
                const int row = bm0 + wr * 128 + i * 32 + (reg & 3) + 8 * (reg >> 2) + erow0;
                float v = acc[i][j][reg];
                if constexpr (MODE == 0) {
                    if (row < Mvalid && colBase < Nvalid)
                        ((__bf16*)Cv)[(size_t)row * ldc + colBase] = (__bf16)v;
                } else {
                    v += (float)bias[colBase];
                    v = v > 0.f ? v : 0.f;
                    ((__bf16*)Cv)[(size_t)row * ldc + colBase] = (__bf16)v;
                }
            }
        }
    }
}

// ---------------------------------------------------------------------------
// 128x128 kernel (R5) — used for GEMM3 where N=2048 would give too few
// 256-wide blocks (256 = 1/CU). MODE 2: +bias, store fp32.
// ---------------------------------------------------------------------------
__global__ __launch_bounds__(256)
void gemm_nt_128(const __bf16* __restrict__ A, int lda,
                 const __bf16* __restrict__ B, int ldb,
                 float* __restrict__ C, int ldc,
                 const __bf16* __restrict__ bias,
                 int K)
{
    __shared__ bf16x8 As[128 * 8];   // 16 KB
    __shared__ bf16x8 Bs[128 * 8];

    const int tid  = threadIdx.x;
    const int wave = tid >> 6;
    const int lane = tid & 63;

    const int bm0 = blockIdx.x * 128;
    const int bn0 = blockIdx.y * 128;

    const int wm = (wave >> 1) * 64;
    const int wn = (wave & 1) * 64;

    const int srow8 = lane >> 3;
    const int sc8   = ((lane & 7) ^ srow8) * 8;

    const __bf16* aptr = A + (size_t)(bm0 + wave * 32 + srow8) * lda + sc8;
    const __bf16* bptr = B + (size_t)(bn0 + wave * 32 + srow8) * ldb + sc8;

    const int fr  = lane & 31;
    const int kh  = lane >> 5;
    const int frs = fr & 7;
    const int aRow0 = (wm + fr) * 8;
    const int aRow1 = (wm + 32 + fr) * 8;
    const int bRow0 = (wn + fr) * 8;
    const int bRow1 = (wn + 32 + fr) * 8;

    f32x16 acc[2][2] = {};

    const int kTiles = K / BK;
    for (int kt = 0; kt < kTiles; ++kt) {
        #pragma unroll
        for (int i = 0; i < 4; ++i) {
            gload_lds16(aptr + (size_t)(8 * i) * lda,
                        (__bf16*)&As[(wave * 32 + 8 * i) * 8]);
            gload_lds16(bptr + (size_t)(8 * i) * ldb,
                        (__bf16*)&Bs[(wave * 32 + 8 * i) * 8]);
        }
        aptr += BK;
        bptr += BK;
        __builtin_amdgcn_s_waitcnt(0);
        __syncthreads();

        #pragma unroll
        for (int w = 0; w < 4; ++w) {
            const int sl = (2 * w + kh) ^ frs;
            bf16x8 a0 = As[aRow0 + sl];
            bf16x8 a1 = As[aRow1 + sl];
            bf16x8 b0 = Bs[bRow0 + sl];
            bf16x8 b1 = Bs[bRow1 + sl];
            acc[0][0] = __builtin_amdgcn_mfma_f32_32x32x16_bf16(a0, b0, acc[0][0], 0, 0, 0);
            acc[0][1] = __builtin_amdgcn_mfma_f32_32x32x16_bf16(a0, b1, acc[0][1], 0, 0, 0);
            acc[1][0] = __builtin_amdgcn_mfma_f32_32x32x16_bf16(a1, b0, acc[1][0], 0, 0, 0);
            acc[1][1] = __builtin_amdgcn_mfma_f32_32x32x16_bf16(a1, b1, acc[1][1], 0, 0, 0);
        }

        __syncthreads();
    }

    const int ecol  = lane & 31;
    const int erow0 = 4 * kh;
    #pragma unroll
    for (int i = 0; i < 2; ++i) {
        #pragma unroll
        for (int j = 0; j < 2; ++j) {
            const int colBase = bn0 + wn + j * 32 + ecol;
            #pragma unroll
            for (int reg = 0; reg < 16; ++reg) {
                const int row = bm0 + wm + i * 32 + (reg & 3) + 8 * (reg >> 2) + erow0;
                float v = acc[i][j][reg] + (float)bias[colBase];
                C[(size_t)row * ldc + colBase] = v;
            }
        }
    }
}

// fp32 (rows x cols) -> zero-padded bf16 (prows x pcols), row-major
__global__ void pad_cvt_bf16(const float* __restrict__ in, __bf16* __restrict__ out,
                             int rows, int cols, int pcols, int total)
{
    int idx = blockIdx.x * blockDim.x + threadIdx.x;
    if (idx >= total) return;
    int r = idx / pcols;
    int c = idx - r * pcols;
    float v = (r < rows && c < cols) ? in[(size_t)r * cols + c] : 0.0f;
    out[idx] = (__bf16)v;
}

// straight fp32 -> bf16, vectorized x4
__global__ void cvt_bf16_vec(const float4* __restrict__ in, bf16x4* __restrict__ out, int n4)
{
    int i = blockIdx.x * blockDim.x + threadIdx.x;
    if (i >= n4) return;
    float4 v = in[i];
    bf16x4 o;
    o.x = (__bf16)v.x; o.y = (__bf16)v.y; o.z = (__bf16)v.z; o.w = (__bf16)v.w;
    out[i] = o;
}

extern "C" void kernel_launch(void* const* d_in, const int* in_sizes, int n_in,
                              void* d_out, int out_size, void* d_ws, size_t ws_size,
                              hipStream_t stream)
{
    const float* x  = (const float*)d_in[0];
    const float* V1 = (const float*)d_in[1];
    const float* V2 = (const float*)d_in[2];
    float* out = (float*)d_out;

    char* ws = (char*)d_ws;
    const size_t vbElems  = (size_t)SIZE_N * SIZE_N;   // 33,570,436
    const size_t padElems = (size_t)PN * PK;           // 17,334,272

    size_t off = 0;
    __bf16* Vb = (__bf16*)(ws + off);
    off += ((vbElems * 2 + 255) / 256) * 256;          // 67,141,120
    __bf16* V1b = (__bf16*)(ws + off);                 // live only through GEMM1
    __bf16* V2b = V1b + padElems;
    __bf16* hb  = (__bf16*)(ws + off);                 // overlaps V1b/V2b (live after GEMM1)
    off += ((2 * padElems * 2 + 255) / 256) * 256;     // 69,337,088
    __bf16* xb = (__bf16*)(ws + off);
    off += (size_t)BATCH * D_IN * 2;
    if (ws_size < off) return;  // workspace too small -> fail validation cleanly

    // fp32 -> bf16 conversions (V1/V2 zero-padded to PN x PK)
    {
        int total  = (int)padElems;
        int blocks = (total + 255) / 256;
        pad_cvt_bf16<<<blocks, 256, 0, stream>>>(V1, V1b, SIZE_N, SIZE_M, PK, total);
        pad_cvt_bf16<<<blocks, 256, 0, stream>>>(V2, V2b, SIZE_N, SIZE_M, PK, total);
        int n4 = BATCH * D_IN / 4;
        cvt_bf16_vec<<<(n4 + 255) / 256, 256, 0, stream>>>((const float4*)x, (bf16x4*)xb, n4);
    }

    // GEMM1: V = V1 * V2^T  (padded 5888x5888x2944, store valid 5794x5794 as bf16 flat)
    gemm_nt_big<0><<<dim3(PN / 256, PN / 128), 256, 0, stream>>>(
        V1b, PK, V2b, PK, (void*)Vb, SIZE_N, (const __bf16*)nullptr, PK, SIZE_N, SIZE_N);

    // GEMM2: h = relu(x * W1^T + b1)   (4096 x 8192 x 2048)
    gemm_nt_big<1><<<dim3(BATCH / 256, D_FF / 128), 256, 0, stream>>>(
        xb, D_IN, Vb, D_IN, (void*)hb, D_FF, Vb + OFF_B1, D_IN, BATCH, D_FF);

    // GEMM3: out = h * W2^T + b2       (4096 x 2048 x 8192)
    gemm_nt_128<<<dim3(BATCH / 128, D_OUT / 128), 256, 0, stream>>>(
        hb, D_FF, Vb + OFF_W2, D_FF, out, D_OUT, Vb + OFF_B2, D_FF);
}